// Round 1
// baseline (366.750 us; speedup 1.0000x reference)
//
#include <hip/hip_runtime.h>

// Problem constants (from reference)
constexpr int B = 256, L = 500, D = 3, C = 32, I = 35, H = 512, O = 15, M = 5;
constexpr int KP1 = 64;  // GEMM1 K-dim (I=35) zero-padded to 4 MFMA k-steps (32x32x16)
constexpr int JP = 48;   // Vt rows stored (only rows 0..34 ever read)
constexpr int KPV = 520; // padded K leading dim for Vt
constexpr int G = 50;    // scan chunks
constexpr int LC = 10;   // L / G

typedef __attribute__((ext_vector_type(8))) _Float16 half8;  // MFMA A/B frag
typedef __attribute__((ext_vector_type(2))) _Float16 half2;
typedef __attribute__((ext_vector_type(16))) float f32x16;   // 32x32 C/D frag

// -------------------------------------------------------------------------
// k0x: xT[l][b][k] fp16, K padded to 64 (zeros k>=35). (unchanged, proven)
// -------------------------------------------------------------------------
__global__ __launch_bounds__(256) void k0x(const float* __restrict__ inp,
                                           const float* __restrict__ z,
                                           _Float16* __restrict__ xT) {
  const int l = blockIdx.x, tid = threadIdx.x;  // tid = b
  __shared__ _Float16 xs[B][38];
  const float* ip = inp + ((size_t)tid * L + l) * D;
  const float4* zp = (const float4*)(z + ((size_t)tid * L + l) * C);
  xs[tid][0] = (_Float16)ip[0];
  xs[tid][1] = (_Float16)ip[1];
  xs[tid][2] = (_Float16)ip[2];
#pragma unroll
  for (int q = 0; q < 8; ++q) {
    float4 v = zp[q];
    xs[tid][D + q * 4 + 0] = (_Float16)v.x;
    xs[tid][D + q * 4 + 1] = (_Float16)v.y;
    xs[tid][D + q * 4 + 2] = (_Float16)v.z;
    xs[tid][D + q * 4 + 3] = (_Float16)v.w;
  }
  __syncthreads();
  unsigned int* dst = (unsigned int*)(xT + (size_t)l * B * KP1);
  for (int f = tid; f < B * KP1 / 2; f += 256) {
    int b = f >> 5, k = (f & 31) * 2;
    unsigned int lo = (k < I)     ? *(const unsigned short*)&xs[b][k]     : 0u;
    unsigned int hi = (k + 1 < I) ? *(const unsigned short*)&xs[b][k + 1] : 0u;
    dst[f] = lo | (hi << 16);
  }
}

// -------------------------------------------------------------------------
// k0w: Wt[l][h][k] fp16 (K padded 64) from W_enc fp32 [l][i][h]. (unchanged)
// -------------------------------------------------------------------------
__global__ __launch_bounds__(256) void k0w(const float* __restrict__ W,
                                           _Float16* __restrict__ Wt) {
  const int l = blockIdx.x, tid = threadIdx.x;
  __shared__ _Float16 ws[H][37];
  for (int f = tid; f < I * H; f += 256) {
    int i = f >> 9, h = f & 511;
    ws[h][i] = (_Float16)W[((size_t)l * I + i) * H + h];
  }
  __syncthreads();
  unsigned int* dst = (unsigned int*)(Wt + (size_t)l * H * KP1);
  for (int f = tid; f < H * KP1 / 2; f += 256) {
    int h = f >> 5, k = (f & 31) * 2;
    unsigned int lo = (k < I)     ? *(const unsigned short*)&ws[h][k]     : 0u;
    unsigned int hi = (k + 1 < I) ? *(const unsigned short*)&ws[h][k + 1] : 0u;
    dst[f] = lo | (hi << 16);
  }
}

// -------------------------------------------------------------------------
// k0v: Vt[l][j][k] fp16 [L][48][520] = V^T per step. (unchanged, proven)
// -------------------------------------------------------------------------
__global__ __launch_bounds__(256) void k0v(const float* __restrict__ Vmu,
                                           const float* __restrict__ Vsg,
                                           const float* __restrict__ Vpi,
                                           _Float16* __restrict__ Vt) {
  const int l = blockIdx.x, tid = threadIdx.x;
  __shared__ __align__(16) _Float16 Vs[JP * KPV];  // 49,920 B
  for (int f = tid; f < (JP * KPV) / 8; f += 256) ((uint4*)Vs)[f] = (uint4){0, 0, 0, 0};
  __syncthreads();
  const float* vm = Vmu + (size_t)l * H * O;
  const float* vs = Vsg + (size_t)l * H * O;
  const float* vp = Vpi + (size_t)l * H * M;
  for (int idx = tid; idx < H * O; idx += 256) {
    int k = idx / O, j = idx - k * O;
    Vs[j * KPV + k]       = (_Float16)vm[idx];
    Vs[(O + j) * KPV + k] = (_Float16)vs[idx];
  }
  for (int idx = tid; idx < H * M; idx += 256) {
    int k = idx / M, j = idx - k * M;
    Vs[(2 * O + j) * KPV + k] = (_Float16)vp[idx];
  }
  __syncthreads();
  uint4* dst = (uint4*)(Vt + (size_t)l * JP * KPV);
  for (int f = tid; f < (JP * KPV) / 8; f += 256) dst[f] = ((const uint4*)Vs)[f];
}

// -------------------------------------------------------------------------
// kA: chunk partial sums S_g^T[h][b] = sum_{l in chunk} (x[l] @ W[l])^T, fp16.
// c^T orientation: A = Wt rows(h), B = xT cols(b); wave = 128h x 32b; acc in
// regs across the 10 l's. Grid 448 with XCD swizzle (chunk g -> XCD g%8 so
// its 8 b-blocks share one L2 for the W chunk slice).
// -------------------------------------------------------------------------
__global__ __launch_bounds__(256, 2) void kA(const _Float16* __restrict__ xT,
                                             const _Float16* __restrict__ Wt,
                                             _Float16* __restrict__ S) {
  const int idx = blockIdx.x;
  const int g = ((idx >> 6) << 3) + (idx & 7);
  if (g >= G) return;
  const int b0 = ((idx >> 3) & 7) * 32;
  const int w = threadIdx.x >> 6, lane = threadIdx.x & 63;
  const int ln31 = lane & 31, hi32 = lane >> 5;

  f32x16 acc[4];
#pragma unroll
  for (int mt = 0; mt < 4; ++mt)
#pragma unroll
    for (int r = 0; r < 16; ++r) acc[mt][r] = 0.f;

  for (int t = 0; t < LC; ++t) {
    const int l = g * LC + t;
    const _Float16* Xb = xT + ((size_t)l * B + b0 + ln31) * KP1 + 8 * hi32;
    const _Float16* Wb = Wt + ((size_t)l * H + 128 * w + ln31) * KP1 + 8 * hi32;
    half8 xf[4];
#pragma unroll
    for (int kt = 0; kt < 4; ++kt) xf[kt] = *(const half8*)(Xb + 16 * kt);
#pragma unroll
    for (int mt = 0; mt < 4; ++mt) {
      const _Float16* Wr = Wb + (size_t)mt * 32 * KP1;
#pragma unroll
      for (int kt = 0; kt < 4; ++kt) {
        half8 wf = *(const half8*)(Wr + 16 * kt);
        acc[mt] = __builtin_amdgcn_mfma_f32_32x32x16_f16(wf, xf[kt], acc[mt], 0, 0, 0);
      }
    }
  }
  // store S^T[g][h][b]: D layout col(b)=ln31, row(h)=(r&3)+8*(r>>2)+4*hi32
  _Float16* Sp = S + ((size_t)g * H + 128 * w) * B + b0 + ln31;
#pragma unroll
  for (int mt = 0; mt < 4; ++mt)
#pragma unroll
    for (int r = 0; r < 16; ++r) {
      const int hl = 32 * mt + (r & 3) + 8 * (r >> 2) + 4 * hi32;
      Sp[(size_t)hl * B] = (_Float16)acc[mt][r];
    }
}

// -------------------------------------------------------------------------
// kS: exclusive scan over the G chunk sums per (h,b), + b_enc.
// Acc[g][h][b] (f32) = b_enc[h] + sum_{g'<g} S[g'][h][b]. 131072 threads.
// -------------------------------------------------------------------------
__global__ __launch_bounds__(256) void kS(const _Float16* __restrict__ S,
                                          const float* __restrict__ benc,
                                          float* __restrict__ Acc) {
  const int t = blockIdx.x * 256 + threadIdx.x;  // B*H threads
  const int b = t & (B - 1), h = t >> 8;
  float run = benc[h];
  const _Float16* sp = S + (size_t)h * B + b;
  float* ap = Acc + (size_t)h * B + b;
  constexpr size_t stride = (size_t)H * B;
#pragma unroll 5
  for (int g = 0; g < G; ++g) {
    ap[g * stride] = run;          // exclusive: write before adding own chunk
    run += (float)sp[g * stride];
  }
}

// -------------------------------------------------------------------------
// kB: fused scan + projection per chunk. Running state a^T[h][b] lives in
// MFMA accumulators (4x f32x16 per wave = 128h x 32b). Per l:
//   h = relu(a): cvt_pkrtz + v_permlane32_swap -> 32x32x16 B-frags IN REGS
//   out^T[j][b] partial (K = wave's 128h) via MFMA, A = Vt rows j
//   cross-wave K-reduce via ds_add_f32 into LDS chunk-out buffer
//   a += (x[l] @ W[l])^T  (MFMA accumulate in place)
// No barriers in the l-loop; one coalesced writeout at chunk end.
// -------------------------------------------------------------------------
__global__ __launch_bounds__(256, 2) void kB(const _Float16* __restrict__ xT,
                                             const _Float16* __restrict__ Wt,
                                             const _Float16* __restrict__ Vt,
                                             const float* __restrict__ Acc,
                                             const float* __restrict__ bmu,
                                             const float* __restrict__ bsg,
                                             const float* __restrict__ bpi,
                                             float* __restrict__ out) {
  const int idx = blockIdx.x;
  const int g = ((idx >> 6) << 3) + (idx & 7);
  if (g >= G) return;
  const int b0 = ((idx >> 3) & 7) * 32;
  const int tid = threadIdx.x;
  const int w = tid >> 6, lane = tid & 63;
  const int ln31 = lane & 31, hi32 = lane >> 5;

  // row stride 361 words: (9b + j) spreads 64 lanes 2-per-bank (free)
  __shared__ float outb[32][LC * 36 + 1];
  for (int f = tid; f < 32 * (LC * 36 + 1); f += 256) ((float*)outb)[f] = 0.f;

  // load running state a = Acc[g] into D-layout accumulators
  f32x16 acc[4];
  const float* Ap = Acc + ((size_t)g * H + 128 * w) * B + b0 + ln31;
#pragma unroll
  for (int mt = 0; mt < 4; ++mt)
#pragma unroll
    for (int r = 0; r < 16; ++r) {
      const int hl = 32 * mt + (r & 3) + 8 * (r >> 2) + 4 * hi32;
      acc[mt][r] = Ap[(size_t)hl * B];
    }
  __syncthreads();  // outb zero-init visible

  for (int t = 0; t < LC; ++t) {
    const int l = g * LC + t;
    // ---- projection: out^T[j][b] += V^T[j][h] * relu(a)[h][b] ----
    const _Float16* Vb = Vt + (size_t)l * JP * KPV + 128 * w + 8 * hi32;
    f32x16 o0, o1;
#pragma unroll
    for (int r = 0; r < 16; ++r) { o0[r] = 0.f; o1[r] = 0.f; }
#pragma unroll
    for (int mt = 0; mt < 4; ++mt) {
      // relu + pack: P0[m] = halves(rows 8m+4*hi32+{0,1}), P1[m] = {2,3}
      unsigned P0[4], P1[4];
#pragma unroll
      for (int m = 0; m < 4; ++m) {
        float e0 = fmaxf(acc[mt][4 * m + 0], 0.f);
        float e1 = fmaxf(acc[mt][4 * m + 1], 0.f);
        float e2 = fmaxf(acc[mt][4 * m + 2], 0.f);
        float e3 = fmaxf(acc[mt][4 * m + 3], 0.f);
        P0[m] = __builtin_bit_cast(unsigned, __builtin_amdgcn_cvt_pkrtz(e0, e1));
        P1[m] = __builtin_bit_cast(unsigned, __builtin_amdgcn_cvt_pkrtz(e2, e3));
      }
#pragma unroll
      for (int tl = 0; tl < 2; ++tl) {
        // swap vdst.hi <-> vsrc.lo: after swap(X,Y): X=[X.lo|Y.lo], Y=[X.hi|Y.hi]
        unsigned w0 = P0[2 * tl], w2 = P0[2 * tl + 1];
        unsigned w1 = P1[2 * tl], w3 = P1[2 * tl + 1];
        asm("v_permlane32_swap_b32 %0, %1" : "+v"(w0), "+v"(w2));
        asm("v_permlane32_swap_b32 %0, %1" : "+v"(w1), "+v"(w3));
        half2 a0 = __builtin_bit_cast(half2, w0);
        half2 a1 = __builtin_bit_cast(half2, w1);
        half2 a2 = __builtin_bit_cast(half2, w2);
        half2 a3 = __builtin_bit_cast(half2, w3);
        half8 hb = {a0.x, a0.y, a1.x, a1.y, a2.x, a2.y, a3.x, a3.y};
        const _Float16* Va = Vb + (32 * mt + 16 * tl);
        half8 va0 = *(const half8*)(Va + (size_t)ln31 * KPV);
        half8 va1 = {};
        if (ln31 < 3) va1 = *(const half8*)(Va + (size_t)(32 + ln31) * KPV);  // j=32..34 only
        o0 = __builtin_amdgcn_mfma_f32_32x32x16_f16(va0, hb, o0, 0, 0, 0);
        o1 = __builtin_amdgcn_mfma_f32_32x32x16_f16(va1, hb, o1, 0, 0, 0);
      }
    }
    // cross-wave K-reduction into LDS (j < 35)
#pragma unroll
    for (int r = 0; r < 16; ++r) {
      const int j0 = (r & 3) + 8 * (r >> 2) + 4 * hi32;
      atomicAdd(&outb[ln31][t * 36 + j0], o0[r]);
      if (j0 + 32 < 35) atomicAdd(&outb[ln31][t * 36 + j0 + 32], o1[r]);
    }
    // ---- recurrence: a += (x[l] @ W[l])^T ----
    if (t != LC - 1) {
      const _Float16* Xb = xT + ((size_t)l * B + b0 + ln31) * KP1 + 8 * hi32;
      const _Float16* Wb = Wt + ((size_t)l * H + 128 * w + ln31) * KP1 + 8 * hi32;
      half8 xf[4];
#pragma unroll
      for (int kt = 0; kt < 4; ++kt) xf[kt] = *(const half8*)(Xb + 16 * kt);
#pragma unroll
      for (int mt = 0; mt < 4; ++mt) {
        const _Float16* Wr = Wb + (size_t)mt * 32 * KP1;
#pragma unroll
        for (int kt = 0; kt < 4; ++kt) {
          half8 wf = *(const half8*)(Wr + 16 * kt);
          acc[mt] = __builtin_amdgcn_mfma_f32_32x32x16_f16(wf, xf[kt], acc[mt], 0, 0, 0);
        }
      }
    }
  }
  __syncthreads();
  // coalesced writeout: per b-row 350 contiguous floats (10 l x 35 j)
  for (int f = tid; f < 32 * LC * 35; f += 256) {
    const int b = f / (LC * 35);
    const int r = f - b * (LC * 35);
    const int t = r / 35, j = r - 35 * t;
    const int l = g * LC + t;
    const float bias = (j < O) ? bmu[l * O + j]
                     : (j < 2 * O) ? bsg[l * O + (j - O)]
                     : bpi[l * M + (j - 2 * O)];
    out[((size_t)(b0 + b) * L + l) * 35 + j] = outb[b][t * 36 + j] + bias;
  }
}

extern "C" void kernel_launch(void* const* d_in, const int* in_sizes, int n_in,
                              void* d_out, int out_size, void* d_ws, size_t ws_size,
                              hipStream_t stream) {
  const float* inp  = (const float*)d_in[0];
  const float* z    = (const float*)d_in[1];
  const float* Wenc = (const float*)d_in[2];
  const float* benc = (const float*)d_in[3];
  const float* Vmu  = (const float*)d_in[4];
  const float* bmu  = (const float*)d_in[5];
  const float* Vsg  = (const float*)d_in[6];
  const float* bsg  = (const float*)d_in[7];
  const float* Vpi  = (const float*)d_in[8];
  const float* bpi  = (const float*)d_in[9];
  float* out = (float*)d_out;

  // Workspace: xT 16.38 + Wt 32.77 + Vt 24.96 + S 13.11 + Acc 26.21 = 113.4 MB
  char* ws = (char*)d_ws;
  _Float16* xT = (_Float16*)ws;                            // [L][B][64]
  _Float16* Wt = (_Float16*)(ws + 16384000);               // [L][H][64]
  _Float16* Vt = (_Float16*)(ws + 16384000 + 32768000);    // [L][48][520]
  _Float16* S  = (_Float16*)(ws + 74112000);               // [G][H][B] fp16
  float*    Acc = (float*)(ws + 87219200);                 // [G][H][B] f32

  k0x<<<dim3(L), 256, 0, stream>>>(inp, z, xT);
  k0w<<<dim3(L), 256, 0, stream>>>(Wenc, Wt);
  k0v<<<dim3(L), 256, 0, stream>>>(Vmu, Vsg, Vpi, Vt);
  kA<<<dim3(448), 256, 0, stream>>>(xT, Wt, S);
  kS<<<dim3(B * H / 256), 256, 0, stream>>>(S, benc, Acc);
  kB<<<dim3(448), 256, 0, stream>>>(xT, Wt, Vt, Acc, bmu, bsg, bpi, out);
}

// Round 2
// 348.845 us; speedup vs baseline: 1.0513x; 1.0513x over previous
//
#include <hip/hip_runtime.h>

// Problem constants (from reference)
constexpr int B = 256, L = 500, D = 3, C = 32, I = 35, H = 512, O = 15, M = 5;
constexpr int KP1 = 48;  // GEMM1 K-dim (I=35) zero-padded to 3 MFMA k-steps (32x32x16)
constexpr int JP = 48;   // Vt rows stored (only rows 0..34 ever read)
constexpr int KPV = 520; // padded K leading dim for Vt
constexpr int G = 100;   // scan chunks
constexpr int LC = 5;    // L / G

typedef __attribute__((ext_vector_type(8))) _Float16 half8;  // MFMA A/B frag
typedef __attribute__((ext_vector_type(2))) _Float16 half2;
typedef __attribute__((ext_vector_type(16))) float f32x16;   // 32x32 C/D frag

// -------------------------------------------------------------------------
// k0x: xT[l][b][k] fp16, K padded to 48 (zeros k>=35).
// -------------------------------------------------------------------------
__global__ __launch_bounds__(256) void k0x(const float* __restrict__ inp,
                                           const float* __restrict__ z,
                                           _Float16* __restrict__ xT) {
  const int l = blockIdx.x, tid = threadIdx.x;  // tid = b
  __shared__ _Float16 xs[B][38];
  const float* ip = inp + ((size_t)tid * L + l) * D;
  const float4* zp = (const float4*)(z + ((size_t)tid * L + l) * C);
  xs[tid][0] = (_Float16)ip[0];
  xs[tid][1] = (_Float16)ip[1];
  xs[tid][2] = (_Float16)ip[2];
#pragma unroll
  for (int q = 0; q < 8; ++q) {
    float4 v = zp[q];
    xs[tid][D + q * 4 + 0] = (_Float16)v.x;
    xs[tid][D + q * 4 + 1] = (_Float16)v.y;
    xs[tid][D + q * 4 + 2] = (_Float16)v.z;
    xs[tid][D + q * 4 + 3] = (_Float16)v.w;
  }
  __syncthreads();
  unsigned int* dst = (unsigned int*)(xT + (size_t)l * B * KP1);
  for (int f = tid; f < B * (KP1 / 2); f += 256) {
    int b = f / (KP1 / 2), k = (f - b * (KP1 / 2)) * 2;
    unsigned int lo = (k < I)     ? *(const unsigned short*)&xs[b][k]     : 0u;
    unsigned int hi = (k + 1 < I) ? *(const unsigned short*)&xs[b][k + 1] : 0u;
    dst[f] = lo | (hi << 16);
  }
}

// -------------------------------------------------------------------------
// k0w: Wt[l][h][k] fp16 (K padded 48) from W_enc fp32 [l][i][h].
// -------------------------------------------------------------------------
__global__ __launch_bounds__(256) void k0w(const float* __restrict__ W,
                                           _Float16* __restrict__ Wt) {
  const int l = blockIdx.x, tid = threadIdx.x;
  __shared__ _Float16 ws[H][37];
  for (int f = tid; f < I * H; f += 256) {
    int i = f >> 9, h = f & 511;
    ws[h][i] = (_Float16)W[((size_t)l * I + i) * H + h];
  }
  __syncthreads();
  unsigned int* dst = (unsigned int*)(Wt + (size_t)l * H * KP1);
  for (int f = tid; f < H * (KP1 / 2); f += 256) {
    int h = f / (KP1 / 2), k = (f - h * (KP1 / 2)) * 2;
    unsigned int lo = (k < I)     ? *(const unsigned short*)&ws[h][k]     : 0u;
    unsigned int hi = (k + 1 < I) ? *(const unsigned short*)&ws[h][k + 1] : 0u;
    dst[f] = lo | (hi << 16);
  }
}

// -------------------------------------------------------------------------
// k0v: Vt[l][j][k] fp16 [L][48][520] = V^T per step. (unchanged, proven)
// -------------------------------------------------------------------------
__global__ __launch_bounds__(256) void k0v(const float* __restrict__ Vmu,
                                           const float* __restrict__ Vsg,
                                           const float* __restrict__ Vpi,
                                           _Float16* __restrict__ Vt) {
  const int l = blockIdx.x, tid = threadIdx.x;
  __shared__ __align__(16) _Float16 Vs[JP * KPV];  // 49,920 B
  for (int f = tid; f < (JP * KPV) / 8; f += 256) ((uint4*)Vs)[f] = (uint4){0, 0, 0, 0};
  __syncthreads();
  const float* vm = Vmu + (size_t)l * H * O;
  const float* vs = Vsg + (size_t)l * H * O;
  const float* vp = Vpi + (size_t)l * H * M;
  for (int idx = tid; idx < H * O; idx += 256) {
    int k = idx / O, j = idx - k * O;
    Vs[j * KPV + k]       = (_Float16)vm[idx];
    Vs[(O + j) * KPV + k] = (_Float16)vs[idx];
  }
  for (int idx = tid; idx < H * M; idx += 256) {
    int k = idx / M, j = idx - k * M;
    Vs[(2 * O + j) * KPV + k] = (_Float16)vp[idx];
  }
  __syncthreads();
  uint4* dst = (uint4*)(Vt + (size_t)l * JP * KPV);
  for (int f = tid; f < (JP * KPV) / 8; f += 256) dst[f] = ((const uint4*)Vs)[f];
}

// -------------------------------------------------------------------------
// kA: chunk partial sums S_g^T[h][b] = sum_{l in chunk} (x[l] @ W[l])^T, fp16.
// 832 blocks (8 b-blocks x 104 g-slots, 4 dead), XCD swizzle co-locates the
// 8 b-blocks of a chunk on one XCD's L2. Loads hoisted to top of each step.
// -------------------------------------------------------------------------
__global__ __launch_bounds__(256, 3) void kA(const _Float16* __restrict__ xT,
                                             const _Float16* __restrict__ Wt,
                                             _Float16* __restrict__ S) {
  const int idx = blockIdx.x;
  const int g = ((idx >> 6) << 3) + (idx & 7);
  if (g >= G) return;
  const int b0 = ((idx >> 3) & 7) * 32;
  const int w = threadIdx.x >> 6, lane = threadIdx.x & 63;
  const int ln31 = lane & 31, hi32 = lane >> 5;

  f32x16 acc[4];
#pragma unroll
  for (int mt = 0; mt < 4; ++mt)
#pragma unroll
    for (int r = 0; r < 16; ++r) acc[mt][r] = 0.f;

#pragma unroll 1
  for (int t = 0; t < LC; ++t) {
    const int l = g * LC + t;
    const _Float16* Xb = xT + ((size_t)l * B + b0 + ln31) * KP1 + 8 * hi32;
    const _Float16* Wb = Wt + ((size_t)l * H + 128 * w + ln31) * KP1 + 8 * hi32;
    half8 xf[3], wf[12];
#pragma unroll
    for (int kt = 0; kt < 3; ++kt) xf[kt] = *(const half8*)(Xb + 16 * kt);
#pragma unroll
    for (int mt = 0; mt < 4; ++mt)
#pragma unroll
      for (int kt = 0; kt < 3; ++kt)
        wf[mt * 3 + kt] = *(const half8*)(Wb + (size_t)mt * 32 * KP1 + 16 * kt);
#pragma unroll
    for (int mt = 0; mt < 4; ++mt)
#pragma unroll
      for (int kt = 0; kt < 3; ++kt)
        acc[mt] = __builtin_amdgcn_mfma_f32_32x32x16_f16(wf[mt * 3 + kt], xf[kt], acc[mt], 0, 0, 0);
  }
  // store S^T[g][h][b]: D layout col(b)=ln31, row(h)=(r&3)+8*(r>>2)+4*hi32
  _Float16* Sp = S + ((size_t)g * H + 128 * w) * B + b0 + ln31;
#pragma unroll
  for (int mt = 0; mt < 4; ++mt)
#pragma unroll
    for (int r = 0; r < 16; ++r) {
      const int hl = 32 * mt + (r & 3) + 8 * (r >> 2) + 4 * hi32;
      Sp[(size_t)hl * B] = (_Float16)acc[mt][r];
    }
}

// -------------------------------------------------------------------------
// kS: exclusive scan over the G chunk sums per (h,b), + b_enc.
// -------------------------------------------------------------------------
__global__ __launch_bounds__(256) void kS(const _Float16* __restrict__ S,
                                          const float* __restrict__ benc,
                                          float* __restrict__ Acc) {
  const int t = blockIdx.x * 256 + threadIdx.x;  // B*H threads
  const int b = t & (B - 1), h = t >> 8;
  float run = benc[h];
  const _Float16* sp = S + (size_t)h * B + b;
  float* ap = Acc + (size_t)h * B + b;
  constexpr size_t stride = (size_t)H * B;
#pragma unroll 5
  for (int g = 0; g < G; ++g) {
    ap[g * stride] = run;          // exclusive: write before adding own chunk
    run += (float)sp[g * stride];
  }
}

// -------------------------------------------------------------------------
// kB: fused scan + projection per chunk. State a^T[h][b] in MFMA accums.
// Per l-step: hoist ALL loads (va0 32r, xf 12r, wf 48r) to the top so they
// fly under the pack VALU + proj MFMA phase; va1 (j=32..34, 3 lanes) loaded
// transiently. ~140 arch VGPR + 96 AGPR = 236 -> 2 waves/SIMD, no spill.
// -------------------------------------------------------------------------
__global__ __launch_bounds__(256, 2) void kB(const _Float16* __restrict__ xT,
                                             const _Float16* __restrict__ Wt,
                                             const _Float16* __restrict__ Vt,
                                             const float* __restrict__ Acc,
                                             const float* __restrict__ bmu,
                                             const float* __restrict__ bsg,
                                             const float* __restrict__ bpi,
                                             float* __restrict__ out) {
  const int idx = blockIdx.x;
  const int g = ((idx >> 6) << 3) + (idx & 7);
  if (g >= G) return;
  const int b0 = ((idx >> 3) & 7) * 32;
  const int tid = threadIdx.x;
  const int w = tid >> 6, lane = tid & 63;
  const int ln31 = lane & 31, hi32 = lane >> 5;

  // row stride 181 words (odd): lanes spread conflict-free
  __shared__ float outb[32][LC * 36 + 1];
  for (int f = tid; f < 32 * (LC * 36 + 1); f += 256) ((float*)outb)[f] = 0.f;

  // load running state a = Acc[g] into D-layout accumulators
  f32x16 acc[4];
  const float* Ap = Acc + ((size_t)g * H + 128 * w) * B + b0 + ln31;
#pragma unroll
  for (int mt = 0; mt < 4; ++mt)
#pragma unroll
    for (int r = 0; r < 16; ++r) {
      const int hl = 32 * mt + (r & 3) + 8 * (r >> 2) + 4 * hi32;
      acc[mt][r] = Ap[(size_t)hl * B];
    }
  __syncthreads();  // outb zero-init visible

#pragma unroll 1
  for (int t = 0; t < LC; ++t) {
    const int l = g * LC + t;
    // ---- issue all loads for this step up front (fly under pack+proj) ----
    const _Float16* Vb = Vt + (size_t)l * JP * KPV + 128 * w + 8 * hi32;
    half8 va0[8];
#pragma unroll
    for (int s = 0; s < 8; ++s)
      va0[s] = *(const half8*)(Vb + 16 * s + (size_t)ln31 * KPV);
    half8 xf[3], wf[12];
    if (t != LC - 1) {
      const _Float16* Xb = xT + ((size_t)l * B + b0 + ln31) * KP1 + 8 * hi32;
      const _Float16* Wb = Wt + ((size_t)l * H + 128 * w + ln31) * KP1 + 8 * hi32;
#pragma unroll
      for (int kt = 0; kt < 3; ++kt) xf[kt] = *(const half8*)(Xb + 16 * kt);
#pragma unroll
      for (int mt = 0; mt < 4; ++mt)
#pragma unroll
        for (int kt = 0; kt < 3; ++kt)
          wf[mt * 3 + kt] = *(const half8*)(Wb + (size_t)mt * 32 * KP1 + 16 * kt);
    }
    // ---- projection: out^T[j][b] += V^T[j][h] * relu(a)[h][b] ----
    f32x16 o0, o1;
#pragma unroll
    for (int r = 0; r < 16; ++r) { o0[r] = 0.f; o1[r] = 0.f; }
#pragma unroll
    for (int mt = 0; mt < 4; ++mt) {
      // relu + pack: P0[m] = halves(rows 8m+4*hi32+{0,1}), P1[m] = {2,3}
      unsigned P0[4], P1[4];
#pragma unroll
      for (int m = 0; m < 4; ++m) {
        float e0 = fmaxf(acc[mt][4 * m + 0], 0.f);
        float e1 = fmaxf(acc[mt][4 * m + 1], 0.f);
        float e2 = fmaxf(acc[mt][4 * m + 2], 0.f);
        float e3 = fmaxf(acc[mt][4 * m + 3], 0.f);
        P0[m] = __builtin_bit_cast(unsigned, __builtin_amdgcn_cvt_pkrtz(e0, e1));
        P1[m] = __builtin_bit_cast(unsigned, __builtin_amdgcn_cvt_pkrtz(e2, e3));
      }
#pragma unroll
      for (int tl = 0; tl < 2; ++tl) {
        const _Float16* Va = Vb + (32 * mt + 16 * tl);
        half8 va1 = {};
        if (ln31 < 3) va1 = *(const half8*)(Va + (size_t)(32 + ln31) * KPV);  // j=32..34
        // swap vdst.hi <-> vsrc.lo: after swap(X,Y): X=[X.lo|Y.lo], Y=[X.hi|Y.hi]
        unsigned w0 = P0[2 * tl], w2 = P0[2 * tl + 1];
        unsigned w1 = P1[2 * tl], w3 = P1[2 * tl + 1];
        asm("v_permlane32_swap_b32 %0, %1" : "+v"(w0), "+v"(w2));
        asm("v_permlane32_swap_b32 %0, %1" : "+v"(w1), "+v"(w3));
        half2 a0 = __builtin_bit_cast(half2, w0);
        half2 a1 = __builtin_bit_cast(half2, w1);
        half2 a2 = __builtin_bit_cast(half2, w2);
        half2 a3 = __builtin_bit_cast(half2, w3);
        half8 hb = {a0.x, a0.y, a1.x, a1.y, a2.x, a2.y, a3.x, a3.y};
        o0 = __builtin_amdgcn_mfma_f32_32x32x16_f16(va0[2 * mt + tl], hb, o0, 0, 0, 0);
        o1 = __builtin_amdgcn_mfma_f32_32x32x16_f16(va1, hb, o1, 0, 0, 0);
      }
    }
    // cross-wave K-reduction into LDS (j < 35)
#pragma unroll
    for (int r = 0; r < 16; ++r) {
      const int j0 = (r & 3) + 8 * (r >> 2) + 4 * hi32;
      atomicAdd(&outb[ln31][t * 36 + j0], o0[r]);
      if (j0 + 32 < 35) atomicAdd(&outb[ln31][t * 36 + j0 + 32], o1[r]);
    }
    // ---- recurrence: a += (x[l] @ W[l])^T ----
    if (t != LC - 1) {
#pragma unroll
      for (int mt = 0; mt < 4; ++mt)
#pragma unroll
        for (int kt = 0; kt < 3; ++kt)
          acc[mt] = __builtin_amdgcn_mfma_f32_32x32x16_f16(wf[mt * 3 + kt], xf[kt], acc[mt], 0, 0, 0);
    }
  }
  __syncthreads();
  // coalesced writeout: per b-row LC*35 contiguous floats
  for (int f = tid; f < 32 * LC * 35; f += 256) {
    const int b = f / (LC * 35);
    const int r = f - b * (LC * 35);
    const int t = r / 35, j = r - 35 * t;
    const int l = g * LC + t;
    const float bias = (j < O) ? bmu[l * O + j]
                     : (j < 2 * O) ? bsg[l * O + (j - O)]
                     : bpi[l * M + (j - 2 * O)];
    out[((size_t)(b0 + b) * L + l) * 35 + j] = outb[b][t * 36 + j] + bias;
  }
}

extern "C" void kernel_launch(void* const* d_in, const int* in_sizes, int n_in,
                              void* d_out, int out_size, void* d_ws, size_t ws_size,
                              hipStream_t stream) {
  const float* inp  = (const float*)d_in[0];
  const float* z    = (const float*)d_in[1];
  const float* Wenc = (const float*)d_in[2];
  const float* benc = (const float*)d_in[3];
  const float* Vmu  = (const float*)d_in[4];
  const float* bmu  = (const float*)d_in[5];
  const float* Vsg  = (const float*)d_in[6];
  const float* bsg  = (const float*)d_in[7];
  const float* Vpi  = (const float*)d_in[8];
  const float* bpi  = (const float*)d_in[9];
  float* out = (float*)d_out;

  // Workspace: xT 12.29 + Wt 24.58 + Vt 24.96 + S 26.21 + Acc 52.43 = 140.5 MB
  char* ws = (char*)d_ws;
  _Float16* xT  = (_Float16*)ws;                   // [L][B][48]
  _Float16* Wt  = (_Float16*)(ws + 12288000);      // [L][H][48]
  _Float16* Vt  = (_Float16*)(ws + 36864000);      // [L][48][520]
  _Float16* S   = (_Float16*)(ws + 61824000);      // [G][H][B] fp16
  float*    Acc = (float*)(ws + 88038400);         // [G][H][B] f32

  k0x<<<dim3(L), 256, 0, stream>>>(inp, z, xT);
  k0w<<<dim3(L), 256, 0, stream>>>(Wenc, Wt);
  k0v<<<dim3(L), 256, 0, stream>>>(Vmu, Vsg, Vpi, Vt);
  kA<<<dim3(832), 256, 0, stream>>>(xT, Wt, S);
  kS<<<dim3(B * H / 256), 256, 0, stream>>>(S, benc, Acc);
  kB<<<dim3(832), 256, 0, stream>>>(xT, Wt, Vt, Acc, bmu, bsg, bpi, out);
}

// Round 4
// 266.402 us; speedup vs baseline: 1.3767x; 1.3095x over previous
//
#include <hip/hip_runtime.h>

// Problem constants (from reference)
constexpr int B = 256, L = 500, D = 3, C = 32, I = 35, H = 512, O = 15, M = 5;
constexpr int KP1 = 48;  // GEMM1 K-dim (I=35) zero-padded to 3 MFMA k-steps (32x32x16)
constexpr int JP = 48;   // Vt rows stored (only rows 0..34 ever read)
constexpr int KPV = 520; // padded K leading dim for Vt
constexpr int G = 100;   // scan chunks
constexpr int LC = 5;    // L / G

typedef __attribute__((ext_vector_type(8))) _Float16 half8;  // MFMA A/B frag
typedef __attribute__((ext_vector_type(2))) _Float16 half2;
typedef __attribute__((ext_vector_type(16))) float f32x16;   // 32x32 C/D frag

// -------------------------------------------------------------------------
// k0x: xT[l][b][k] fp16, K padded to 48 (zeros k>=35).
// -------------------------------------------------------------------------
__global__ __launch_bounds__(256) void k0x(const float* __restrict__ inp,
                                           const float* __restrict__ z,
                                           _Float16* __restrict__ xT) {
  const int l = blockIdx.x, tid = threadIdx.x;  // tid = b
  __shared__ _Float16 xs[B][38];
  const float* ip = inp + ((size_t)tid * L + l) * D;
  const float4* zp = (const float4*)(z + ((size_t)tid * L + l) * C);
  xs[tid][0] = (_Float16)ip[0];
  xs[tid][1] = (_Float16)ip[1];
  xs[tid][2] = (_Float16)ip[2];
#pragma unroll
  for (int q = 0; q < 8; ++q) {
    float4 v = zp[q];
    xs[tid][D + q * 4 + 0] = (_Float16)v.x;
    xs[tid][D + q * 4 + 1] = (_Float16)v.y;
    xs[tid][D + q * 4 + 2] = (_Float16)v.z;
    xs[tid][D + q * 4 + 3] = (_Float16)v.w;
  }
  __syncthreads();
  unsigned int* dst = (unsigned int*)(xT + (size_t)l * B * KP1);
  for (int f = tid; f < B * (KP1 / 2); f += 256) {
    int b = f / (KP1 / 2), k = (f - b * (KP1 / 2)) * 2;
    unsigned int lo = (k < I)     ? *(const unsigned short*)&xs[b][k]     : 0u;
    unsigned int hi = (k + 1 < I) ? *(const unsigned short*)&xs[b][k + 1] : 0u;
    dst[f] = lo | (hi << 16);
  }
}

// -------------------------------------------------------------------------
// k0w: Wt[l][h][k] fp16 (K padded 48) from W_enc fp32 [l][i][h].
// -------------------------------------------------------------------------
__global__ __launch_bounds__(256) void k0w(const float* __restrict__ W,
                                           _Float16* __restrict__ Wt) {
  const int l = blockIdx.x, tid = threadIdx.x;
  __shared__ _Float16 ws[H][37];
  for (int f = tid; f < I * H; f += 256) {
    int i = f >> 9, h = f & 511;
    ws[h][i] = (_Float16)W[((size_t)l * I + i) * H + h];
  }
  __syncthreads();
  unsigned int* dst = (unsigned int*)(Wt + (size_t)l * H * KP1);
  for (int f = tid; f < H * (KP1 / 2); f += 256) {
    int h = f / (KP1 / 2), k = (f - h * (KP1 / 2)) * 2;
    unsigned int lo = (k < I)     ? *(const unsigned short*)&ws[h][k]     : 0u;
    unsigned int hi = (k + 1 < I) ? *(const unsigned short*)&ws[h][k + 1] : 0u;
    dst[f] = lo | (hi << 16);
  }
}

// -------------------------------------------------------------------------
// k0v: Vt[l][j][k] fp16 [L][48][520] = V^T per step. (unchanged, proven)
// -------------------------------------------------------------------------
__global__ __launch_bounds__(256) void k0v(const float* __restrict__ Vmu,
                                           const float* __restrict__ Vsg,
                                           const float* __restrict__ Vpi,
                                           _Float16* __restrict__ Vt) {
  const int l = blockIdx.x, tid = threadIdx.x;
  __shared__ __align__(16) _Float16 Vs[JP * KPV];  // 49,920 B
  for (int f = tid; f < (JP * KPV) / 8; f += 256) ((uint4*)Vs)[f] = (uint4){0, 0, 0, 0};
  __syncthreads();
  const float* vm = Vmu + (size_t)l * H * O;
  const float* vs = Vsg + (size_t)l * H * O;
  const float* vp = Vpi + (size_t)l * H * M;
  for (int idx = tid; idx < H * O; idx += 256) {
    int k = idx / O, j = idx - k * O;
    Vs[j * KPV + k]       = (_Float16)vm[idx];
    Vs[(O + j) * KPV + k] = (_Float16)vs[idx];
  }
  for (int idx = tid; idx < H * M; idx += 256) {
    int k = idx / M, j = idx - k * M;
    Vs[(2 * O + j) * KPV + k] = (_Float16)vp[idx];
  }
  __syncthreads();
  uint4* dst = (uint4*)(Vt + (size_t)l * JP * KPV);
  for (int f = tid; f < (JP * KPV) / 8; f += 256) dst[f] = ((const uint4*)Vs)[f];
}

// -------------------------------------------------------------------------
// kA: chunk partial sums S_g^T[h][b] = sum_{l in chunk} (x[l] @ W[l])^T, fp16.
// (unchanged, proven)
// -------------------------------------------------------------------------
__global__ __launch_bounds__(256, 3) void kA(const _Float16* __restrict__ xT,
                                             const _Float16* __restrict__ Wt,
                                             _Float16* __restrict__ S) {
  const int idx = blockIdx.x;
  const int g = ((idx >> 6) << 3) + (idx & 7);
  if (g >= G) return;
  const int b0 = ((idx >> 3) & 7) * 32;
  const int w = threadIdx.x >> 6, lane = threadIdx.x & 63;
  const int ln31 = lane & 31, hi32 = lane >> 5;

  f32x16 acc[4];
#pragma unroll
  for (int mt = 0; mt < 4; ++mt)
#pragma unroll
    for (int r = 0; r < 16; ++r) acc[mt][r] = 0.f;

#pragma unroll 1
  for (int t = 0; t < LC; ++t) {
    const int l = g * LC + t;
    const _Float16* Xb = xT + ((size_t)l * B + b0 + ln31) * KP1 + 8 * hi32;
    const _Float16* Wb = Wt + ((size_t)l * H + 128 * w + ln31) * KP1 + 8 * hi32;
    half8 xf[3], wf[12];
#pragma unroll
    for (int kt = 0; kt < 3; ++kt) xf[kt] = *(const half8*)(Xb + 16 * kt);
#pragma unroll
    for (int mt = 0; mt < 4; ++mt)
#pragma unroll
      for (int kt = 0; kt < 3; ++kt)
        wf[mt * 3 + kt] = *(const half8*)(Wb + (size_t)mt * 32 * KP1 + 16 * kt);
#pragma unroll
    for (int mt = 0; mt < 4; ++mt)
#pragma unroll
      for (int kt = 0; kt < 3; ++kt)
        acc[mt] = __builtin_amdgcn_mfma_f32_32x32x16_f16(wf[mt * 3 + kt], xf[kt], acc[mt], 0, 0, 0);
  }
  // store S^T[g][h][b]: D layout col(b)=ln31, row(h)=(r&3)+8*(r>>2)+4*hi32
  _Float16* Sp = S + ((size_t)g * H + 128 * w) * B + b0 + ln31;
#pragma unroll
  for (int mt = 0; mt < 4; ++mt)
#pragma unroll
    for (int r = 0; r < 16; ++r) {
      const int hl = 32 * mt + (r & 3) + 8 * (r >> 2) + 4 * hi32;
      Sp[(size_t)hl * B] = (_Float16)acc[mt][r];
    }
}

// -------------------------------------------------------------------------
// kS: exclusive scan over the G chunk sums per (h,b), + b_enc. (unchanged)
// -------------------------------------------------------------------------
__global__ __launch_bounds__(256) void kS(const _Float16* __restrict__ S,
                                          const float* __restrict__ benc,
                                          float* __restrict__ Acc) {
  const int t = blockIdx.x * 256 + threadIdx.x;  // B*H threads
  const int b = t & (B - 1), h = t >> 8;
  float run = benc[h];
  const _Float16* sp = S + (size_t)h * B + b;
  float* ap = Acc + (size_t)h * B + b;
  constexpr size_t stride = (size_t)H * B;
#pragma unroll 5
  for (int g = 0; g < G; ++g) {
    ap[g * stride] = run;          // exclusive: write before adding own chunk
    run += (float)sp[g * stride];
  }
}

// -------------------------------------------------------------------------
// kB: fused scan + projection per chunk. State a^T[h][b] in MFMA accums.
// Round-4: NO atomics (round 2's atomicAdd = CAS spin loop; round 3's
// ds_add_f32 asm broke correctness — compiler can't track asm DS ops).
// Each wave writes partials to its own LDS slab po[w][32][37] with plain
// ds_writes (stride 37 = conflict-free), barrier, then 256 threads sum the
// 4 partials and write straight to global with bias. 2 barriers/step.
// -------------------------------------------------------------------------
__global__ __launch_bounds__(256, 2) void kB(const _Float16* __restrict__ xT,
                                             const _Float16* __restrict__ Wt,
                                             const _Float16* __restrict__ Vt,
                                             const float* __restrict__ Acc,
                                             const float* __restrict__ bmu,
                                             const float* __restrict__ bsg,
                                             const float* __restrict__ bpi,
                                             float* __restrict__ out) {
  const int idx = blockIdx.x;
  const int g = ((idx >> 6) << 3) + (idx & 7);
  if (g >= G) return;
  const int b0 = ((idx >> 3) & 7) * 32;
  const int tid = threadIdx.x;
  const int w = tid >> 6, lane = tid & 63;
  const int ln31 = lane & 31, hi32 = lane >> 5;

  // per-wave partial slabs; stride 37 (odd, ==5 mod 32) -> bank-bijective
  __shared__ float po[4][32][37];  // 18,944 B

  // load running state a = Acc[g] into D-layout accumulators
  f32x16 acc[4];
  const float* Ap = Acc + ((size_t)g * H + 128 * w) * B + b0 + ln31;
#pragma unroll
  for (int mt = 0; mt < 4; ++mt)
#pragma unroll
    for (int r = 0; r < 16; ++r) {
      const int hl = 32 * mt + (r & 3) + 8 * (r >> 2) + 4 * hi32;
      acc[mt][r] = Ap[(size_t)hl * B];
    }

#pragma unroll 1
  for (int t = 0; t < LC; ++t) {
    const int l = g * LC + t;
    // ---- issue ALL loads for this step up front (fly under pack+proj) ----
    const _Float16* Vb = Vt + (size_t)l * JP * KPV + 128 * w + 8 * hi32;
    half8 va0[8];
#pragma unroll
    for (int s = 0; s < 8; ++s)
      va0[s] = *(const half8*)(Vb + 16 * s + (size_t)ln31 * KPV);
    half8 va1[8];
#pragma unroll
    for (int s = 0; s < 8; ++s) {
      va1[s] = half8{};
      if (ln31 < 3)  // j = 32..34 tail rows
        va1[s] = *(const half8*)(Vb + 16 * s + (size_t)(32 + ln31) * KPV);
    }
    half8 xf[3], wf[12];
    if (t != LC - 1) {
      const _Float16* Xb = xT + ((size_t)l * B + b0 + ln31) * KP1 + 8 * hi32;
      const _Float16* Wb = Wt + ((size_t)l * H + 128 * w + ln31) * KP1 + 8 * hi32;
#pragma unroll
      for (int kt = 0; kt < 3; ++kt) xf[kt] = *(const half8*)(Xb + 16 * kt);
#pragma unroll
      for (int mt = 0; mt < 4; ++mt)
#pragma unroll
        for (int kt = 0; kt < 3; ++kt)
          wf[mt * 3 + kt] = *(const half8*)(Wb + (size_t)mt * 32 * KP1 + 16 * kt);
    }
    // ---- projection: out^T[j][b] += V^T[j][h] * relu(a)[h][b] ----
    f32x16 o0, o1;
#pragma unroll
    for (int r = 0; r < 16; ++r) { o0[r] = 0.f; o1[r] = 0.f; }
#pragma unroll
    for (int mt = 0; mt < 4; ++mt) {
      // relu + pack: P0[m] = halves(rows 8m+4*hi32+{0,1}), P1[m] = {2,3}
      unsigned P0[4], P1[4];
#pragma unroll
      for (int m = 0; m < 4; ++m) {
        float e0 = fmaxf(acc[mt][4 * m + 0], 0.f);
        float e1 = fmaxf(acc[mt][4 * m + 1], 0.f);
        float e2 = fmaxf(acc[mt][4 * m + 2], 0.f);
        float e3 = fmaxf(acc[mt][4 * m + 3], 0.f);
        P0[m] = __builtin_bit_cast(unsigned, __builtin_amdgcn_cvt_pkrtz(e0, e1));
        P1[m] = __builtin_bit_cast(unsigned, __builtin_amdgcn_cvt_pkrtz(e2, e3));
      }
#pragma unroll
      for (int tl = 0; tl < 2; ++tl) {
        // swap vdst.hi <-> vsrc.lo: after swap(X,Y): X=[X.lo|Y.lo], Y=[X.hi|Y.hi]
        unsigned w0 = P0[2 * tl], w2 = P0[2 * tl + 1];
        unsigned w1 = P1[2 * tl], w3 = P1[2 * tl + 1];
        asm("v_permlane32_swap_b32 %0, %1" : "+v"(w0), "+v"(w2));
        asm("v_permlane32_swap_b32 %0, %1" : "+v"(w1), "+v"(w3));
        half2 a0 = __builtin_bit_cast(half2, w0);
        half2 a1 = __builtin_bit_cast(half2, w1);
        half2 a2 = __builtin_bit_cast(half2, w2);
        half2 a3 = __builtin_bit_cast(half2, w3);
        half8 hb = {a0.x, a0.y, a1.x, a1.y, a2.x, a2.y, a3.x, a3.y};
        o0 = __builtin_amdgcn_mfma_f32_32x32x16_f16(va0[2 * mt + tl], hb, o0, 0, 0, 0);
        o1 = __builtin_amdgcn_mfma_f32_32x32x16_f16(va1[2 * mt + tl], hb, o1, 0, 0, 0);
      }
    }
    // ---- per-wave partials to LDS (plain stores, compiler-tracked) ----
    float* pw = &po[w][ln31][0];
#pragma unroll
    for (int r = 0; r < 16; ++r) {
      const int j0 = (r & 3) + 8 * (r >> 2) + 4 * hi32;
      pw[j0] = o0[r];
      if (j0 + 32 < 35) pw[j0 + 32] = o1[r];
    }
    // ---- recurrence: a += (x[l] @ W[l])^T (issues while DS drains) ----
    if (t != LC - 1) {
#pragma unroll
      for (int mt = 0; mt < 4; ++mt)
#pragma unroll
        for (int kt = 0; kt < 3; ++kt)
          acc[mt] = __builtin_amdgcn_mfma_f32_32x32x16_f16(wf[mt * 3 + kt], xf[kt], acc[mt], 0, 0, 0);
    }
    __syncthreads();
    // ---- cross-wave reduce + bias + direct global write ----
    for (int f = tid; f < 32 * 35; f += 256) {
      const int b = f / 35, j = f - 35 * b;
      const float s = po[0][b][j] + po[1][b][j] + po[2][b][j] + po[3][b][j];
      const float bias = (j < O) ? bmu[l * O + j]
                       : (j < 2 * O) ? bsg[l * O + (j - O)]
                       : bpi[l * M + (j - 2 * O)];
      out[((size_t)(b0 + b) * L + l) * 35 + j] = s + bias;
    }
    __syncthreads();  // protect po before next step's writes
  }
}

extern "C" void kernel_launch(void* const* d_in, const int* in_sizes, int n_in,
                              void* d_out, int out_size, void* d_ws, size_t ws_size,
                              hipStream_t stream) {
  const float* inp  = (const float*)d_in[0];
  const float* z    = (const float*)d_in[1];
  const float* Wenc = (const float*)d_in[2];
  const float* benc = (const float*)d_in[3];
  const float* Vmu  = (const float*)d_in[4];
  const float* bmu  = (const float*)d_in[5];
  const float* Vsg  = (const float*)d_in[6];
  const float* bsg  = (const float*)d_in[7];
  const float* Vpi  = (const float*)d_in[8];
  const float* bpi  = (const float*)d_in[9];
  float* out = (float*)d_out;

  // Workspace: xT 12.29 + Wt 24.58 + Vt 24.96 + S 26.21 + Acc 52.43 = 140.5 MB
  char* ws = (char*)d_ws;
  _Float16* xT  = (_Float16*)ws;                   // [L][B][48]
  _Float16* Wt  = (_Float16*)(ws + 12288000);      // [L][H][48]
  _Float16* Vt  = (_Float16*)(ws + 36864000);      // [L][48][520]
  _Float16* S   = (_Float16*)(ws + 61824000);      // [G][H][B] fp16
  float*    Acc = (float*)(ws + 88038400);         // [G][H][B] f32

  k0x<<<dim3(L), 256, 0, stream>>>(inp, z, xT);
  k0w<<<dim3(L), 256, 0, stream>>>(Wenc, Wt);
  k0v<<<dim3(L), 256, 0, stream>>>(Vmu, Vsg, Vpi, Vt);
  kA<<<dim3(832), 256, 0, stream>>>(xT, Wt, S);
  kS<<<dim3(B * H / 256), 256, 0, stream>>>(S, benc, Acc);
  kB<<<dim3(832), 256, 0, stream>>>(xT, Wt, Vt, Acc, bmu, bsg, bpi, out);
}

// Round 5
// 252.220 us; speedup vs baseline: 1.4541x; 1.0562x over previous
//
#include <hip/hip_runtime.h>

// Problem constants (from reference)
constexpr int B = 256, L = 500, D = 3, C = 32, I = 35, H = 512, O = 15, M = 5;
constexpr int KP1 = 48;  // GEMM1 K-dim (I=35) zero-padded to 3 MFMA k-steps (32x32x16)
constexpr int JP = 48;   // Vt rows stored (only rows 0..34 ever read)
constexpr int KPV = 520; // padded K leading dim for Vt
constexpr int G = 100;   // scan chunks
constexpr int LC = 5;    // L / G

typedef __attribute__((ext_vector_type(8))) _Float16 half8;  // MFMA A/B frag
typedef __attribute__((ext_vector_type(2))) _Float16 half2;
typedef __attribute__((ext_vector_type(16))) float f32x16;   // 32x32 C/D frag

// -------------------------------------------------------------------------
// k0x: xT[l][b][k] fp16, K padded to 48 (zeros k>=35). (proven)
// -------------------------------------------------------------------------
__global__ __launch_bounds__(256) void k0x(const float* __restrict__ inp,
                                           const float* __restrict__ z,
                                           _Float16* __restrict__ xT) {
  const int l = blockIdx.x, tid = threadIdx.x;  // tid = b
  __shared__ _Float16 xs[B][38];
  const float* ip = inp + ((size_t)tid * L + l) * D;
  const float4* zp = (const float4*)(z + ((size_t)tid * L + l) * C);
  xs[tid][0] = (_Float16)ip[0];
  xs[tid][1] = (_Float16)ip[1];
  xs[tid][2] = (_Float16)ip[2];
#pragma unroll
  for (int q = 0; q < 8; ++q) {
    float4 v = zp[q];
    xs[tid][D + q * 4 + 0] = (_Float16)v.x;
    xs[tid][D + q * 4 + 1] = (_Float16)v.y;
    xs[tid][D + q * 4 + 2] = (_Float16)v.z;
    xs[tid][D + q * 4 + 3] = (_Float16)v.w;
  }
  __syncthreads();
  unsigned int* dst = (unsigned int*)(xT + (size_t)l * B * KP1);
  for (int f = tid; f < B * (KP1 / 2); f += 256) {
    int b = f / (KP1 / 2), k = (f - b * (KP1 / 2)) * 2;
    unsigned int lo = (k < I)     ? *(const unsigned short*)&xs[b][k]     : 0u;
    unsigned int hi = (k + 1 < I) ? *(const unsigned short*)&xs[b][k + 1] : 0u;
    dst[f] = lo | (hi << 16);
  }
}

// -------------------------------------------------------------------------
// k0w: Wt[l][h][k] fp16 (K padded 48) from W_enc fp32 [l][i][h]. (proven)
// -------------------------------------------------------------------------
__global__ __launch_bounds__(256) void k0w(const float* __restrict__ W,
                                           _Float16* __restrict__ Wt) {
  const int l = blockIdx.x, tid = threadIdx.x;
  __shared__ _Float16 ws[H][37];
  for (int f = tid; f < I * H; f += 256) {
    int i = f >> 9, h = f & 511;
    ws[h][i] = (_Float16)W[((size_t)l * I + i) * H + h];
  }
  __syncthreads();
  unsigned int* dst = (unsigned int*)(Wt + (size_t)l * H * KP1);
  for (int f = tid; f < H * (KP1 / 2); f += 256) {
    int h = f / (KP1 / 2), k = (f - h * (KP1 / 2)) * 2;
    unsigned int lo = (k < I)     ? *(const unsigned short*)&ws[h][k]     : 0u;
    unsigned int hi = (k + 1 < I) ? *(const unsigned short*)&ws[h][k + 1] : 0u;
    dst[f] = lo | (hi << 16);
  }
}

// -------------------------------------------------------------------------
// k0v: Vt[l][j][k] fp16 [L][48][520] = V^T per step. (proven)
// -------------------------------------------------------------------------
__global__ __launch_bounds__(256) void k0v(const float* __restrict__ Vmu,
                                           const float* __restrict__ Vsg,
                                           const float* __restrict__ Vpi,
                                           _Float16* __restrict__ Vt) {
  const int l = blockIdx.x, tid = threadIdx.x;
  __shared__ __align__(16) _Float16 Vs[JP * KPV];  // 49,920 B
  for (int f = tid; f < (JP * KPV) / 8; f += 256) ((uint4*)Vs)[f] = (uint4){0, 0, 0, 0};
  __syncthreads();
  const float* vm = Vmu + (size_t)l * H * O;
  const float* vs = Vsg + (size_t)l * H * O;
  const float* vp = Vpi + (size_t)l * H * M;
  for (int idx = tid; idx < H * O; idx += 256) {
    int k = idx / O, j = idx - k * O;
    Vs[j * KPV + k]       = (_Float16)vm[idx];
    Vs[(O + j) * KPV + k] = (_Float16)vs[idx];
  }
  for (int idx = tid; idx < H * M; idx += 256) {
    int k = idx / M, j = idx - k * M;
    Vs[(2 * O + j) * KPV + k] = (_Float16)vp[idx];
  }
  __syncthreads();
  uint4* dst = (uint4*)(Vt + (size_t)l * JP * KPV);
  for (int f = tid; f < (JP * KPV) / 8; f += 256) dst[f] = ((const uint4*)Vs)[f];
}

// -------------------------------------------------------------------------
// kA: chunk partial sums S_g^T[h][b] = sum_{l in chunk} (x[l] @ W[l])^T, fp16.
// (unchanged, proven)
// -------------------------------------------------------------------------
__global__ __launch_bounds__(256, 3) void kA(const _Float16* __restrict__ xT,
                                             const _Float16* __restrict__ Wt,
                                             _Float16* __restrict__ S) {
  const int idx = blockIdx.x;
  const int g = ((idx >> 6) << 3) + (idx & 7);
  if (g >= G) return;
  const int b0 = ((idx >> 3) & 7) * 32;
  const int w = threadIdx.x >> 6, lane = threadIdx.x & 63;
  const int ln31 = lane & 31, hi32 = lane >> 5;

  f32x16 acc[4];
#pragma unroll
  for (int mt = 0; mt < 4; ++mt)
#pragma unroll
    for (int r = 0; r < 16; ++r) acc[mt][r] = 0.f;

#pragma unroll 1
  for (int t = 0; t < LC; ++t) {
    const int l = g * LC + t;
    const _Float16* Xb = xT + ((size_t)l * B + b0 + ln31) * KP1 + 8 * hi32;
    const _Float16* Wb = Wt + ((size_t)l * H + 128 * w + ln31) * KP1 + 8 * hi32;
    half8 xf[3], wf[12];
#pragma unroll
    for (int kt = 0; kt < 3; ++kt) xf[kt] = *(const half8*)(Xb + 16 * kt);
#pragma unroll
    for (int mt = 0; mt < 4; ++mt)
#pragma unroll
      for (int kt = 0; kt < 3; ++kt)
        wf[mt * 3 + kt] = *(const half8*)(Wb + (size_t)mt * 32 * KP1 + 16 * kt);
#pragma unroll
    for (int mt = 0; mt < 4; ++mt)
#pragma unroll
      for (int kt = 0; kt < 3; ++kt)
        acc[mt] = __builtin_amdgcn_mfma_f32_32x32x16_f16(wf[mt * 3 + kt], xf[kt], acc[mt], 0, 0, 0);
  }
  // store S^T[g][h][b]: D layout col(b)=ln31, row(h)=(r&3)+8*(r>>2)+4*hi32
  _Float16* Sp = S + ((size_t)g * H + 128 * w) * B + b0 + ln31;
#pragma unroll
  for (int mt = 0; mt < 4; ++mt)
#pragma unroll
    for (int r = 0; r < 16; ++r) {
      const int hl = 32 * mt + (r & 3) + 8 * (r >> 2) + 4 * hi32;
      Sp[(size_t)hl * B] = (_Float16)acc[mt][r];
    }
}

// -------------------------------------------------------------------------
// kS: exclusive scan over the G chunk sums per (h,b), + b_enc.
// Round-5: Acc stored fp16 (halves write traffic + kB's read traffic).
// -------------------------------------------------------------------------
__global__ __launch_bounds__(256) void kS(const _Float16* __restrict__ S,
                                          const float* __restrict__ benc,
                                          _Float16* __restrict__ Acc) {
  const int t = blockIdx.x * 256 + threadIdx.x;  // B*H threads
  const int b = t & (B - 1), h = t >> 8;
  float run = benc[h];
  const _Float16* sp = S + (size_t)h * B + b;
  _Float16* ap = Acc + (size_t)h * B + b;
  constexpr size_t stride = (size_t)H * B;
#pragma unroll 5
  for (int g = 0; g < G; ++g) {
    ap[g * stride] = (_Float16)run;  // exclusive: write before adding own chunk
    run += (float)sp[g * stride];
  }
}

// -------------------------------------------------------------------------
// kB: fused scan + projection per chunk. State a^T[h][b] in MFMA accums.
// Round-5: BARRIER-FREE l-loop. Each wave writes per-step partials (fp16,
// packed-pair DS writes) into its private slab po[w][t][32][36]; waves skew
// freely across the 5 steps (latency hiding). ONE barrier after the loop,
// then a single fused reduce: 4 LDS reads + LDS bias + 700B-contiguous
// global stores. Bias staged to LDS once per block (kills per-step branchy
// global gathers). Acc read as fp16.
// -------------------------------------------------------------------------
__global__ __launch_bounds__(256, 2) void kB(const _Float16* __restrict__ xT,
                                             const _Float16* __restrict__ Wt,
                                             const _Float16* __restrict__ Vt,
                                             const _Float16* __restrict__ Acc,
                                             const float* __restrict__ bmu,
                                             const float* __restrict__ bsg,
                                             const float* __restrict__ bpi,
                                             float* __restrict__ out) {
  const int idx = blockIdx.x;
  const int g = ((idx >> 6) << 3) + (idx & 7);
  if (g >= G) return;
  const int b0 = ((idx >> 3) & 7) * 32;
  const int tid = threadIdx.x;
  const int w = tid >> 6, lane = tid & 63;
  const int ln31 = lane & 31, hi32 = lane >> 5;

  __shared__ _Float16 po[4][LC][32][36];  // 46,080 B per-wave partial slabs
  __shared__ float bias_s[LC][35];        // 700 B

  // stage bias once per block (3-way branch runs once, not per step)
  if (tid < LC * 35) {
    const int t = tid / 35, j = tid - 35 * t, l = g * LC + t;
    bias_s[t][j] = (j < O) ? bmu[l * O + j]
                 : (j < 2 * O) ? bsg[l * O + (j - O)]
                 : bpi[l * M + (j - 2 * O)];
  }

  // load running state a = Acc[g] (fp16) into D-layout accumulators
  f32x16 acc[4];
  const _Float16* Ap = Acc + ((size_t)g * H + 128 * w) * B + b0 + ln31;
#pragma unroll
  for (int mt = 0; mt < 4; ++mt)
#pragma unroll
    for (int r = 0; r < 16; ++r) {
      const int hl = 32 * mt + (r & 3) + 8 * (r >> 2) + 4 * hi32;
      acc[mt][r] = (float)Ap[(size_t)hl * B];
    }

#pragma unroll 1
  for (int t = 0; t < LC; ++t) {
    const int l = g * LC + t;
    // ---- issue ALL loads for this step up front ----
    const _Float16* Vb = Vt + (size_t)l * JP * KPV + 128 * w + 8 * hi32;
    half8 va0[8];
#pragma unroll
    for (int s = 0; s < 8; ++s)
      va0[s] = *(const half8*)(Vb + 16 * s + (size_t)ln31 * KPV);
    half8 va1[8];
#pragma unroll
    for (int s = 0; s < 8; ++s) {
      va1[s] = half8{};
      if (ln31 < 3)  // j = 32..34 tail rows
        va1[s] = *(const half8*)(Vb + 16 * s + (size_t)(32 + ln31) * KPV);
    }
    half8 xf[3], wf[12];
    if (t != LC - 1) {
      const _Float16* Xb = xT + ((size_t)l * B + b0 + ln31) * KP1 + 8 * hi32;
      const _Float16* Wb = Wt + ((size_t)l * H + 128 * w + ln31) * KP1 + 8 * hi32;
#pragma unroll
      for (int kt = 0; kt < 3; ++kt) xf[kt] = *(const half8*)(Xb + 16 * kt);
#pragma unroll
      for (int mt = 0; mt < 4; ++mt)
#pragma unroll
        for (int kt = 0; kt < 3; ++kt)
          wf[mt * 3 + kt] = *(const half8*)(Wb + (size_t)mt * 32 * KP1 + 16 * kt);
    }
    // ---- projection: out^T[j][b] += V^T[j][h] * relu(a)[h][b] ----
    f32x16 o0, o1;
#pragma unroll
    for (int r = 0; r < 16; ++r) { o0[r] = 0.f; o1[r] = 0.f; }
#pragma unroll
    for (int mt = 0; mt < 4; ++mt) {
      // relu + pack: P0[m] = halves(rows 8m+4*hi32+{0,1}), P1[m] = {2,3}
      unsigned P0[4], P1[4];
#pragma unroll
      for (int m = 0; m < 4; ++m) {
        float e0 = fmaxf(acc[mt][4 * m + 0], 0.f);
        float e1 = fmaxf(acc[mt][4 * m + 1], 0.f);
        float e2 = fmaxf(acc[mt][4 * m + 2], 0.f);
        float e3 = fmaxf(acc[mt][4 * m + 3], 0.f);
        P0[m] = __builtin_bit_cast(unsigned, __builtin_amdgcn_cvt_pkrtz(e0, e1));
        P1[m] = __builtin_bit_cast(unsigned, __builtin_amdgcn_cvt_pkrtz(e2, e3));
      }
#pragma unroll
      for (int tl = 0; tl < 2; ++tl) {
        // swap vdst.hi <-> vsrc.lo: after swap(X,Y): X=[X.lo|Y.lo], Y=[X.hi|Y.hi]
        unsigned w0 = P0[2 * tl], w2 = P0[2 * tl + 1];
        unsigned w1 = P1[2 * tl], w3 = P1[2 * tl + 1];
        asm("v_permlane32_swap_b32 %0, %1" : "+v"(w0), "+v"(w2));
        asm("v_permlane32_swap_b32 %0, %1" : "+v"(w1), "+v"(w3));
        half2 a0 = __builtin_bit_cast(half2, w0);
        half2 a1 = __builtin_bit_cast(half2, w1);
        half2 a2 = __builtin_bit_cast(half2, w2);
        half2 a3 = __builtin_bit_cast(half2, w3);
        half8 hb = {a0.x, a0.y, a1.x, a1.y, a2.x, a2.y, a3.x, a3.y};
        o0 = __builtin_amdgcn_mfma_f32_32x32x16_f16(va0[2 * mt + tl], hb, o0, 0, 0, 0);
        o1 = __builtin_amdgcn_mfma_f32_32x32x16_f16(va1[2 * mt + tl], hb, o1, 0, 0, 0);
      }
    }
    // ---- per-wave partials to private slab (packed fp16 pairs, no sync) --
    _Float16* pw = &po[w][t][ln31][0];
#pragma unroll
    for (int r = 0; r < 16; r += 2) {
      const int j0 = (r & 3) + 8 * (r >> 2) + 4 * hi32;  // even; pair j0,j0+1
      *(unsigned*)&pw[j0] =
          __builtin_bit_cast(unsigned, __builtin_amdgcn_cvt_pkrtz(o0[r], o0[r + 1]));
    }
    if (hi32 == 0) {  // o1 rows j=32,33,34 live only in hi32==0 lanes
      *(unsigned*)&pw[32] =
          __builtin_bit_cast(unsigned, __builtin_amdgcn_cvt_pkrtz(o1[0], o1[1]));
      pw[34] = (_Float16)o1[2];
    }
    // ---- recurrence: a += (x[l] @ W[l])^T ----
    if (t != LC - 1) {
#pragma unroll
      for (int mt = 0; mt < 4; ++mt)
#pragma unroll
        for (int kt = 0; kt < 3; ++kt)
          acc[mt] = __builtin_amdgcn_mfma_f32_32x32x16_f16(wf[mt * 3 + kt], xf[kt], acc[mt], 0, 0, 0);
    }
  }
  __syncthreads();  // one barrier: po + bias_s visible
  // ---- fused reduce: per b-row 175 contiguous floats (5 l x 35 j) ----
  for (int f = tid; f < 32 * LC * 35; f += 256) {
    const int b = f / (LC * 35);
    const int r = f - b * (LC * 35);
    const int t = r / 35, j = r - 35 * t;
    const float s = (float)po[0][t][b][j] + (float)po[1][t][b][j] +
                    (float)po[2][t][b][j] + (float)po[3][t][b][j];
    out[((size_t)(b0 + b) * L + g * LC + t) * 35 + j] = s + bias_s[t][j];
  }
}

extern "C" void kernel_launch(void* const* d_in, const int* in_sizes, int n_in,
                              void* d_out, int out_size, void* d_ws, size_t ws_size,
                              hipStream_t stream) {
  const float* inp  = (const float*)d_in[0];
  const float* z    = (const float*)d_in[1];
  const float* Wenc = (const float*)d_in[2];
  const float* benc = (const float*)d_in[3];
  const float* Vmu  = (const float*)d_in[4];
  const float* bmu  = (const float*)d_in[5];
  const float* Vsg  = (const float*)d_in[6];
  const float* bsg  = (const float*)d_in[7];
  const float* Vpi  = (const float*)d_in[8];
  const float* bpi  = (const float*)d_in[9];
  float* out = (float*)d_out;

  // Workspace: xT 12.29 + Wt 24.58 + Vt 24.96 + S 26.21 + Acc(fp16) 26.21 = 114.3 MB
  char* ws = (char*)d_ws;
  _Float16* xT  = (_Float16*)ws;                   // [L][B][48]
  _Float16* Wt  = (_Float16*)(ws + 12288000);      // [L][H][48]
  _Float16* Vt  = (_Float16*)(ws + 36864000);      // [L][48][520]
  _Float16* S   = (_Float16*)(ws + 61824000);      // [G][H][B] fp16
  _Float16* Acc = (_Float16*)(ws + 88038400);      // [G][H][B] fp16

  k0x<<<dim3(L), 256, 0, stream>>>(inp, z, xT);
  k0w<<<dim3(L), 256, 0, stream>>>(Wenc, Wt);
  k0v<<<dim3(L), 256, 0, stream>>>(Vmu, Vsg, Vpi, Vt);
  kA<<<dim3(832), 256, 0, stream>>>(xT, Wt, S);
  kS<<<dim3(B * H / 256), 256, 0, stream>>>(S, benc, Acc);
  kB<<<dim3(832), 256, 0, stream>>>(xT, Wt, Vt, Acc, bmu, bsg, bpi, out);
}

// Round 6
// 238.768 us; speedup vs baseline: 1.5360x; 1.0563x over previous
//
#include <hip/hip_runtime.h>

// Problem constants (from reference)
constexpr int B = 256, L = 500, D = 3, C = 32, I = 35, H = 512, O = 15, M = 5;
constexpr int KP1 = 48;  // GEMM1 K-dim (I=35) zero-padded to 3 MFMA k-steps (32x32x16)
constexpr int JP = 48;   // Vt rows stored (only rows 0..34 ever read)
constexpr int KPV = 520; // padded K leading dim for Vt
constexpr int G = 100;   // scan chunks
constexpr int LC = 5;    // L / G

typedef __attribute__((ext_vector_type(8))) _Float16 half8;  // MFMA A/B frag
typedef __attribute__((ext_vector_type(2))) _Float16 half2;
typedef __attribute__((ext_vector_type(16))) float f32x16;   // 32x32 C/D frag

// -------------------------------------------------------------------------
// kPrep: all three layout preps in ONE dispatch (1500 blocks).
//   role 0 (bx <  L):  xT[l][b][k]  — LDS-free: per-thread row pack + 6x16B
//   role 1 (bx < 2L):  Wt[l][h][k]  — LDS-free: coalesced reads (lane=h),
//                                      per-thread row pack + 6x16B stores
//   role 2 (else):     Vt[l][j][k]  — proven LDS scatter-transpose
// -------------------------------------------------------------------------
__global__ __launch_bounds__(256) void kPrep(const float* __restrict__ inp,
                                             const float* __restrict__ z,
                                             const float* __restrict__ W,
                                             const float* __restrict__ Vmu,
                                             const float* __restrict__ Vsg,
                                             const float* __restrict__ Vpi,
                                             _Float16* __restrict__ xT,
                                             _Float16* __restrict__ Wt,
                                             _Float16* __restrict__ Vt) {
  const int bx = blockIdx.x, tid = threadIdx.x;
  __shared__ __align__(16) _Float16 Vs[JP * KPV];  // 49,920 B (role 2 only)

  if (bx < L) {
    // ---- role 0: xT ----
    const int l = bx, b = tid;
    float e[36];
    const float* ip = inp + ((size_t)b * L + l) * D;
    e[0] = ip[0]; e[1] = ip[1]; e[2] = ip[2];
    const float4* zp = (const float4*)(z + ((size_t)b * L + l) * C);
#pragma unroll
    for (int q = 0; q < 8; ++q) {
      float4 v = zp[q];
      e[D + 4 * q + 0] = v.x; e[D + 4 * q + 1] = v.y;
      e[D + 4 * q + 2] = v.z; e[D + 4 * q + 3] = v.w;
    }
    e[35] = 0.f;
    unsigned u[24];
#pragma unroll
    for (int q = 0; q < 18; ++q)
      u[q] = __builtin_bit_cast(unsigned, __builtin_amdgcn_cvt_pkrtz(e[2 * q], e[2 * q + 1]));
#pragma unroll
    for (int q = 18; q < 24; ++q) u[q] = 0u;
    uint4* dst = (uint4*)(xT + ((size_t)l * B + b) * KP1);
#pragma unroll
    for (int q = 0; q < 6; ++q) dst[q] = ((const uint4*)u)[q];
  } else if (bx < 2 * L) {
    // ---- role 1: Wt ----
    const int l = bx - L;
#pragma unroll
    for (int hp = 0; hp < 2; ++hp) {
      const int h = tid + 256 * hp;
      float v[36];
#pragma unroll
      for (int i = 0; i < I; ++i) v[i] = W[((size_t)l * I + i) * H + h];  // coalesced
      v[35] = 0.f;
      unsigned u[24];
#pragma unroll
      for (int q = 0; q < 18; ++q)
        u[q] = __builtin_bit_cast(unsigned, __builtin_amdgcn_cvt_pkrtz(v[2 * q], v[2 * q + 1]));
#pragma unroll
      for (int q = 18; q < 24; ++q) u[q] = 0u;
      uint4* dst = (uint4*)(Wt + ((size_t)l * H + h) * KP1);
#pragma unroll
      for (int q = 0; q < 6; ++q) dst[q] = ((const uint4*)u)[q];
    }
  } else {
    // ---- role 2: Vt (proven LDS path) ----
    const int l = bx - 2 * L;
    for (int f = tid; f < (JP * KPV) / 8; f += 256) ((uint4*)Vs)[f] = (uint4){0, 0, 0, 0};
    __syncthreads();
    const float* vm = Vmu + (size_t)l * H * O;
    const float* vs = Vsg + (size_t)l * H * O;
    const float* vp = Vpi + (size_t)l * H * M;
    for (int idx = tid; idx < H * O; idx += 256) {
      int k = idx / O, j = idx - k * O;
      Vs[j * KPV + k]       = (_Float16)vm[idx];
      Vs[(O + j) * KPV + k] = (_Float16)vs[idx];
    }
    for (int idx = tid; idx < H * M; idx += 256) {
      int k = idx / M, j = idx - k * M;
      Vs[(2 * O + j) * KPV + k] = (_Float16)vp[idx];
    }
    __syncthreads();
    uint4* dst = (uint4*)(Vt + (size_t)l * JP * KPV);
    for (int f = tid; f < (JP * KPV) / 8; f += 256) dst[f] = ((const uint4*)Vs)[f];
  }
}

// -------------------------------------------------------------------------
// kA: chunk partial sums S_g^T[h][b] = sum_{l in chunk} (x[l] @ W[l])^T, fp16.
// Round-6: t-loop fully unrolled -> one straight-line region, scheduler
// hoists step-t+1 loads above step-t MFMAs (cross-step pipelining).
// -------------------------------------------------------------------------
__global__ __launch_bounds__(256, 3) void kA(const _Float16* __restrict__ xT,
                                             const _Float16* __restrict__ Wt,
                                             _Float16* __restrict__ S) {
  const int idx = blockIdx.x;
  const int g = ((idx >> 6) << 3) + (idx & 7);
  if (g >= G) return;
  const int b0 = ((idx >> 3) & 7) * 32;
  const int w = threadIdx.x >> 6, lane = threadIdx.x & 63;
  const int ln31 = lane & 31, hi32 = lane >> 5;

  f32x16 acc[4];
#pragma unroll
  for (int mt = 0; mt < 4; ++mt)
#pragma unroll
    for (int r = 0; r < 16; ++r) acc[mt][r] = 0.f;

#pragma unroll
  for (int t = 0; t < LC; ++t) {
    const int l = g * LC + t;
    const _Float16* Xb = xT + ((size_t)l * B + b0 + ln31) * KP1 + 8 * hi32;
    const _Float16* Wb = Wt + ((size_t)l * H + 128 * w + ln31) * KP1 + 8 * hi32;
    half8 xf[3], wf[12];
#pragma unroll
    for (int kt = 0; kt < 3; ++kt) xf[kt] = *(const half8*)(Xb + 16 * kt);
#pragma unroll
    for (int mt = 0; mt < 4; ++mt)
#pragma unroll
      for (int kt = 0; kt < 3; ++kt)
        wf[mt * 3 + kt] = *(const half8*)(Wb + (size_t)mt * 32 * KP1 + 16 * kt);
#pragma unroll
    for (int mt = 0; mt < 4; ++mt)
#pragma unroll
      for (int kt = 0; kt < 3; ++kt)
        acc[mt] = __builtin_amdgcn_mfma_f32_32x32x16_f16(wf[mt * 3 + kt], xf[kt], acc[mt], 0, 0, 0);
  }
  // store S^T[g][h][b]: D layout col(b)=ln31, row(h)=(r&3)+8*(r>>2)+4*hi32
  _Float16* Sp = S + ((size_t)g * H + 128 * w) * B + b0 + ln31;
#pragma unroll
  for (int mt = 0; mt < 4; ++mt)
#pragma unroll
    for (int r = 0; r < 16; ++r) {
      const int hl = 32 * mt + (r & 3) + 8 * (r >> 2) + 4 * hi32;
      Sp[(size_t)hl * B] = (_Float16)acc[mt][r];
    }
}

// -------------------------------------------------------------------------
// kS: exclusive scan over the G chunk sums per (h,b), + b_enc. Acc fp16.
// -------------------------------------------------------------------------
__global__ __launch_bounds__(256) void kS(const _Float16* __restrict__ S,
                                          const float* __restrict__ benc,
                                          _Float16* __restrict__ Acc) {
  const int t = blockIdx.x * 256 + threadIdx.x;  // B*H threads
  const int b = t & (B - 1), h = t >> 8;
  float run = benc[h];
  const _Float16* sp = S + (size_t)h * B + b;
  _Float16* ap = Acc + (size_t)h * B + b;
  constexpr size_t stride = (size_t)H * B;
#pragma unroll 5
  for (int g = 0; g < G; ++g) {
    ap[g * stride] = (_Float16)run;  // exclusive: write before adding own chunk
    run += (float)sp[g * stride];
  }
}

// -------------------------------------------------------------------------
// kB: fused scan + projection per chunk. (frozen from round 5 — proven)
// Barrier-free l-loop; per-wave fp16 partial slabs; one barrier; fused
// reduce with LDS-staged bias and 700B-contiguous stores.
// -------------------------------------------------------------------------
__global__ __launch_bounds__(256, 2) void kB(const _Float16* __restrict__ xT,
                                             const _Float16* __restrict__ Wt,
                                             const _Float16* __restrict__ Vt,
                                             const _Float16* __restrict__ Acc,
                                             const float* __restrict__ bmu,
                                             const float* __restrict__ bsg,
                                             const float* __restrict__ bpi,
                                             float* __restrict__ out) {
  const int idx = blockIdx.x;
  const int g = ((idx >> 6) << 3) + (idx & 7);
  if (g >= G) return;
  const int b0 = ((idx >> 3) & 7) * 32;
  const int tid = threadIdx.x;
  const int w = tid >> 6, lane = tid & 63;
  const int ln31 = lane & 31, hi32 = lane >> 5;

  __shared__ _Float16 po[4][LC][32][36];  // 46,080 B per-wave partial slabs
  __shared__ float bias_s[LC][35];        // 700 B

  // stage bias once per block (3-way branch runs once, not per step)
  if (tid < LC * 35) {
    const int t = tid / 35, j = tid - 35 * t, l = g * LC + t;
    bias_s[t][j] = (j < O) ? bmu[l * O + j]
                 : (j < 2 * O) ? bsg[l * O + (j - O)]
                 : bpi[l * M + (j - 2 * O)];
  }

  // load running state a = Acc[g] (fp16) into D-layout accumulators
  f32x16 acc[4];
  const _Float16* Ap = Acc + ((size_t)g * H + 128 * w) * B + b0 + ln31;
#pragma unroll
  for (int mt = 0; mt < 4; ++mt)
#pragma unroll
    for (int r = 0; r < 16; ++r) {
      const int hl = 32 * mt + (r & 3) + 8 * (r >> 2) + 4 * hi32;
      acc[mt][r] = (float)Ap[(size_t)hl * B];
    }

#pragma unroll 1
  for (int t = 0; t < LC; ++t) {
    const int l = g * LC + t;
    // ---- issue ALL loads for this step up front ----
    const _Float16* Vb = Vt + (size_t)l * JP * KPV + 128 * w + 8 * hi32;
    half8 va0[8];
#pragma unroll
    for (int s = 0; s < 8; ++s)
      va0[s] = *(const half8*)(Vb + 16 * s + (size_t)ln31 * KPV);
    half8 va1[8];
#pragma unroll
    for (int s = 0; s < 8; ++s) {
      va1[s] = half8{};
      if (ln31 < 3)  // j = 32..34 tail rows
        va1[s] = *(const half8*)(Vb + 16 * s + (size_t)(32 + ln31) * KPV);
    }
    half8 xf[3], wf[12];
    if (t != LC - 1) {
      const _Float16* Xb = xT + ((size_t)l * B + b0 + ln31) * KP1 + 8 * hi32;
      const _Float16* Wb = Wt + ((size_t)l * H + 128 * w + ln31) * KP1 + 8 * hi32;
#pragma unroll
      for (int kt = 0; kt < 3; ++kt) xf[kt] = *(const half8*)(Xb + 16 * kt);
#pragma unroll
      for (int mt = 0; mt < 4; ++mt)
#pragma unroll
        for (int kt = 0; kt < 3; ++kt)
          wf[mt * 3 + kt] = *(const half8*)(Wb + (size_t)mt * 32 * KP1 + 16 * kt);
    }
    // ---- projection: out^T[j][b] += V^T[j][h] * relu(a)[h][b] ----
    f32x16 o0, o1;
#pragma unroll
    for (int r = 0; r < 16; ++r) { o0[r] = 0.f; o1[r] = 0.f; }
#pragma unroll
    for (int mt = 0; mt < 4; ++mt) {
      // relu + pack: P0[m] = halves(rows 8m+4*hi32+{0,1}), P1[m] = {2,3}
      unsigned P0[4], P1[4];
#pragma unroll
      for (int m = 0; m < 4; ++m) {
        float e0 = fmaxf(acc[mt][4 * m + 0], 0.f);
        float e1 = fmaxf(acc[mt][4 * m + 1], 0.f);
        float e2 = fmaxf(acc[mt][4 * m + 2], 0.f);
        float e3 = fmaxf(acc[mt][4 * m + 3], 0.f);
        P0[m] = __builtin_bit_cast(unsigned, __builtin_amdgcn_cvt_pkrtz(e0, e1));
        P1[m] = __builtin_bit_cast(unsigned, __builtin_amdgcn_cvt_pkrtz(e2, e3));
      }
#pragma unroll
      for (int tl = 0; tl < 2; ++tl) {
        // swap vdst.hi <-> vsrc.lo: after swap(X,Y): X=[X.lo|Y.lo], Y=[X.hi|Y.hi]
        unsigned w0 = P0[2 * tl], w2 = P0[2 * tl + 1];
        unsigned w1 = P1[2 * tl], w3 = P1[2 * tl + 1];
        asm("v_permlane32_swap_b32 %0, %1" : "+v"(w0), "+v"(w2));
        asm("v_permlane32_swap_b32 %0, %1" : "+v"(w1), "+v"(w3));
        half2 a0 = __builtin_bit_cast(half2, w0);
        half2 a1 = __builtin_bit_cast(half2, w1);
        half2 a2 = __builtin_bit_cast(half2, w2);
        half2 a3 = __builtin_bit_cast(half2, w3);
        half8 hb = {a0.x, a0.y, a1.x, a1.y, a2.x, a2.y, a3.x, a3.y};
        o0 = __builtin_amdgcn_mfma_f32_32x32x16_f16(va0[2 * mt + tl], hb, o0, 0, 0, 0);
        o1 = __builtin_amdgcn_mfma_f32_32x32x16_f16(va1[2 * mt + tl], hb, o1, 0, 0, 0);
      }
    }
    // ---- per-wave partials to private slab (packed fp16 pairs, no sync) --
    _Float16* pw = &po[w][t][ln31][0];
#pragma unroll
    for (int r = 0; r < 16; r += 2) {
      const int j0 = (r & 3) + 8 * (r >> 2) + 4 * hi32;  // even; pair j0,j0+1
      *(unsigned*)&pw[j0] =
          __builtin_bit_cast(unsigned, __builtin_amdgcn_cvt_pkrtz(o0[r], o0[r + 1]));
    }
    if (hi32 == 0) {  // o1 rows j=32,33,34 live only in hi32==0 lanes
      *(unsigned*)&pw[32] =
          __builtin_bit_cast(unsigned, __builtin_amdgcn_cvt_pkrtz(o1[0], o1[1]));
      pw[34] = (_Float16)o1[2];
    }
    // ---- recurrence: a += (x[l] @ W[l])^T ----
    if (t != LC - 1) {
#pragma unroll
      for (int mt = 0; mt < 4; ++mt)
#pragma unroll
        for (int kt = 0; kt < 3; ++kt)
          acc[mt] = __builtin_amdgcn_mfma_f32_32x32x16_f16(wf[mt * 3 + kt], xf[kt], acc[mt], 0, 0, 0);
    }
  }
  __syncthreads();  // one barrier: po + bias_s visible
  // ---- fused reduce: per b-row 175 contiguous floats (5 l x 35 j) ----
  for (int f = tid; f < 32 * LC * 35; f += 256) {
    const int b = f / (LC * 35);
    const int r = f - b * (LC * 35);
    const int t = r / 35, j = r - 35 * t;
    const float s = (float)po[0][t][b][j] + (float)po[1][t][b][j] +
                    (float)po[2][t][b][j] + (float)po[3][t][b][j];
    out[((size_t)(b0 + b) * L + g * LC + t) * 35 + j] = s + bias_s[t][j];
  }
}

extern "C" void kernel_launch(void* const* d_in, const int* in_sizes, int n_in,
                              void* d_out, int out_size, void* d_ws, size_t ws_size,
                              hipStream_t stream) {
  const float* inp  = (const float*)d_in[0];
  const float* z    = (const float*)d_in[1];
  const float* Wenc = (const float*)d_in[2];
  const float* benc = (const float*)d_in[3];
  const float* Vmu  = (const float*)d_in[4];
  const float* bmu  = (const float*)d_in[5];
  const float* Vsg  = (const float*)d_in[6];
  const float* bsg  = (const float*)d_in[7];
  const float* Vpi  = (const float*)d_in[8];
  const float* bpi  = (const float*)d_in[9];
  float* out = (float*)d_out;

  // Workspace: xT 12.29 + Wt 24.58 + Vt 24.96 + S 26.21 + Acc(fp16) 26.21 = 114.3 MB
  char* ws = (char*)d_ws;
  _Float16* xT  = (_Float16*)ws;                   // [L][B][48]
  _Float16* Wt  = (_Float16*)(ws + 12288000);      // [L][H][48]
  _Float16* Vt  = (_Float16*)(ws + 36864000);      // [L][48][520]
  _Float16* S   = (_Float16*)(ws + 61824000);      // [G][H][B] fp16
  _Float16* Acc = (_Float16*)(ws + 88038400);      // [G][H][B] fp16

  kPrep<<<dim3(3 * L), 256, 0, stream>>>(inp, z, Wenc, Vmu, Vsg, Vpi, xT, Wt, Vt);
  kA<<<dim3(832), 256, 0, stream>>>(xT, Wt, S);
  kS<<<dim3(B * H / 256), 256, 0, stream>>>(S, benc, Acc);
  kB<<<dim3(832), 256, 0, stream>>>(xT, Wt, Vt, Acc, bmu, bsg, bpi, out);
}